// Round 2
// baseline (1232.705 us; speedup 1.0000x reference)
//
#include <hip/hip_runtime.h>

#define HH 1024
#define WW 1024
#define NB 16
#define NTH 3
#define SHARP 10.0f
#define ACC_BYTES 4096
#define RBAND 128      // kernel A: band rows
#define XBAND 256      // kernel B: band cols

typedef unsigned int u32;
struct QuadU { u32 lo, hi; };   // lo = (c9f f16 | c9o f16<<16), hi = (c33f | c33o<<16)

__device__ __forceinline__ float sigm(float v, float th){
  return 1.0f / (1.0f + __expf(-SHARP*(v - th)));
}
__device__ __forceinline__ u32 pk(float a, float b){
  _Float16 ha = (_Float16)a, hb = (_Float16)b;
  unsigned short ua, ub;
  __builtin_memcpy(&ua, &ha, 2); __builtin_memcpy(&ub, &hb, 2);
  return (u32)ua | ((u32)ub << 16);
}
__device__ __forceinline__ float2 upk(u32 v){
  unsigned short ua = (unsigned short)(v & 0xffffu), ub = (unsigned short)(v >> 16);
  _Float16 ha, hb;
  __builtin_memcpy(&ha, &ua, 2); __builtin_memcpy(&hb, &ub, 2);
  return make_float2((float)ha, (float)hb);
}

// ---------------- Kernel A: vertical sliding sums + k=1 stats -----------------
__global__ __launch_bounds__(256) void fss_vert(
    const float* __restrict__ fcst, const float* __restrict__ obs,
    QuadU* __restrict__ scr, double* __restrict__ accum, int img_base)
{
  const int x    = blockIdx.x*256 + threadIdx.x;     // column
  const int y0   = blockIdx.y*RBAND;                 // band start row
  const int il   = blockIdx.z;                       // image local in chunk
  const int img  = img_base + il;

  const float* F = fcst + (size_t)img*HH*WW;
  const float* O = obs  + (size_t)img*HH*WW;

  float c9f[3]={0,0,0}, c9o[3]={0,0,0}, c33f[3]={0,0,0}, c33o[3]={0,0,0};
  float k1d[3]={0,0,0}, k1r[3]={0,0,0};

  // warmup: rows y0-16 .. y0+16
  #pragma unroll 1
  for (int r = y0-16; r <= y0+16; ++r){
    const bool in = (r >= 0) && (r < HH);
    const float fv = in ? F[(size_t)r*WW + x] : 0.f;
    const float ov = in ? O[(size_t)r*WW + x] : 0.f;
    const bool in9 = (r >= y0-4) && (r <= y0+4);
    const bool ink1 = (r >= y0) && (r <= y0+4);
    #pragma unroll
    for (int t = 0; t < 3; ++t){
      const float th = 0.5f*(float)t;
      const float ff = in ? sigm(fv, th) : 0.f;
      const float oo = (in && (ov > th)) ? 1.f : 0.f;
      c33f[t] += ff; c33o[t] += oo;
      if (in9){ c9f[t] += ff; c9o[t] += oo; }
      if (ink1){ const float d = ff-oo; k1d[t] += d*d; k1r[t] += ff*ff + oo*oo; }
    }
  }

  // stream band rows in groups of 8 (register-ring staging, transposed flush)
  u32 ringlo[3][8], ringhi[3][8];
  #pragma unroll 1
  for (int yy = 0; yy < RBAND; yy += 8){
    #pragma unroll
    for (int j = 0; j < 8; ++j){
      const int y = y0 + yy + j;
      // stage quad for row y (state currently centered at y)
      #pragma unroll
      for (int t = 0; t < 3; ++t){
        ringlo[t][j] = pk(c9f[t],  c9o[t]);
        ringhi[t][j] = pk(c33f[t], c33o[t]);
      }
      // rows entering/leaving the vertical windows
      const int ri9 = y+5, ro9 = y-4, ri33 = y+17, ro33 = y-16;
      const bool bi9  = (ri9  < HH);
      const bool bo9  = (ro9  >= 0);
      const bool bi33 = (ri33 < HH);
      const bool bo33 = (ro33 >= 0);
      const float fi9  = bi9  ? F[(size_t)ri9 *WW + x] : 0.f;
      const float oi9  = bi9  ? O[(size_t)ri9 *WW + x] : 0.f;
      const float fo9  = bo9  ? F[(size_t)ro9 *WW + x] : 0.f;
      const float oo9  = bo9  ? O[(size_t)ro9 *WW + x] : 0.f;
      const float fi33 = bi33 ? F[(size_t)ri33*WW + x] : 0.f;
      const float oi33 = bi33 ? O[(size_t)ri33*WW + x] : 0.f;
      const float fo33 = bo33 ? F[(size_t)ro33*WW + x] : 0.f;
      const float oo33 = bo33 ? O[(size_t)ro33*WW + x] : 0.f;
      const bool k1on = (ri9 <= y0 + RBAND - 1);   // each row counted exactly once
      #pragma unroll
      for (int t = 0; t < 3; ++t){
        const float th = 0.5f*(float)t;
        const float f_i9  = bi9  ? sigm(fi9,  th) : 0.f;
        const float o_i9  = (bi9  && (oi9  > th)) ? 1.f : 0.f;
        const float f_o9  = bo9  ? sigm(fo9,  th) : 0.f;
        const float o_o9  = (bo9  && (oo9  > th)) ? 1.f : 0.f;
        const float f_i33 = bi33 ? sigm(fi33, th) : 0.f;
        const float o_i33 = (bi33 && (oi33 > th)) ? 1.f : 0.f;
        const float f_o33 = bo33 ? sigm(fo33, th) : 0.f;
        const float o_o33 = (bo33 && (oo33 > th)) ? 1.f : 0.f;
        if (k1on){ const float d = f_i9 - o_i9; k1d[t] += d*d; k1r[t] += f_i9*f_i9 + o_i9*o_i9; }
        c9f[t]  += f_i9  - f_o9;   c9o[t]  += o_i9  - o_o9;
        c33f[t] += f_i33 - f_o33;  c33o[t] += o_i33 - o_o33;
      }
    }
    // flush 8 staged rows per threshold, transposed layout scr[(cl)][x][y]
    #pragma unroll
    for (int t = 0; t < 3; ++t){
      QuadU* p = scr + ((size_t)(il*3 + t)*WW + x)*HH + (y0 + yy);
      uint4* p4 = (uint4*)p;
      p4[0] = make_uint4(ringlo[t][0], ringhi[t][0], ringlo[t][1], ringhi[t][1]);
      p4[1] = make_uint4(ringlo[t][2], ringhi[t][2], ringlo[t][3], ringhi[t][3]);
      p4[2] = make_uint4(ringlo[t][4], ringhi[t][4], ringlo[t][5], ringhi[t][5]);
      p4[3] = make_uint4(ringlo[t][6], ringhi[t][6], ringlo[t][7], ringhi[t][7]);
    }
  }

  // block-reduce k1 stats (6 values) and atomically accumulate
  #pragma unroll
  for (int d = 32; d; d >>= 1){
    #pragma unroll
    for (int t = 0; t < 3; ++t){
      k1d[t] += __shfl_down(k1d[t], (unsigned)d, 64);
      k1r[t] += __shfl_down(k1r[t], (unsigned)d, 64);
    }
  }
  __shared__ float red[4][6];
  const int wv = threadIdx.x >> 6, ln = threadIdx.x & 63;
  if (ln == 0){
    #pragma unroll
    for (int t = 0; t < 3; ++t){ red[wv][2*t] = k1d[t]; red[wv][2*t+1] = k1r[t]; }
  }
  __syncthreads();
  if (threadIdx.x < 6){
    double s = 0.0;
    #pragma unroll
    for (int w = 0; w < 4; ++w) s += (double)red[w][threadIdx.x];
    const int t = threadIdx.x >> 1, which = threadIdx.x & 1;
    atomicAdd(&accum[(size_t)(img*NTH + t)*6 + which], s);
  }
}

// ---------------- Kernel B: horizontal sliding windows + k=9/33 stats ---------
__global__ __launch_bounds__(256) void fss_horiz(
    const QuadU* __restrict__ scr, double* __restrict__ accum, int img_base)
{
  const int x0 = blockIdx.x*XBAND;                  // col band start
  const int y  = blockIdx.y*256 + threadIdx.x;      // row (lane dimension)
  const int cl = blockIdx.z;                        // combo local in chunk
  const int combo = img_base*NTH + cl;

  const QuadU* P = scr + (size_t)cl*WW*HH + y;      // index with u*HH

  float s9f=0, s9o=0, s33f=0, s33o=0;
  #pragma unroll 1
  for (int u = x0-16; u <= x0+16; ++u){
    if (u >= 0 && u < WW){
      const QuadU q = P[(size_t)u*HH];
      const float2 b = upk(q.hi);
      s33f += b.x; s33o += b.y;
      if (u >= x0-4 && u <= x0+4){
        const float2 a = upk(q.lo);
        s9f += a.x; s9o += a.y;
      }
    }
  }

  float a9d=0, a9r=0, a33d=0, a33r=0;
  #pragma unroll 4
  for (int x = x0; x < x0 + XBAND; ++x){
    const float d9 = s9f - s9o;
    a9d += d9*d9;  a9r += s9f*s9f + s9o*s9o;
    const float d33 = s33f - s33o;
    a33d += d33*d33;  a33r += s33f*s33f + s33o*s33o;
    // slide windows to center x+1
    const int ui9 = x+5, uo9 = x-4, ui33 = x+17, uo33 = x-16;
    if (ui9 < WW){ const float2 a = upk(P[(size_t)ui9*HH].lo);  s9f += a.x;  s9o += a.y; }
    if (uo9 >= 0){ const float2 a = upk(P[(size_t)uo9*HH].lo);  s9f -= a.x;  s9o -= a.y; }
    if (ui33 < WW){ const float2 b = upk(P[(size_t)ui33*HH].hi); s33f += b.x; s33o += b.y; }
    if (uo33 >= 0){ const float2 b = upk(P[(size_t)uo33*HH].hi); s33f -= b.x; s33o -= b.y; }
  }

  #pragma unroll
  for (int d = 32; d; d >>= 1){
    a9d  += __shfl_down(a9d,  (unsigned)d, 64);
    a9r  += __shfl_down(a9r,  (unsigned)d, 64);
    a33d += __shfl_down(a33d, (unsigned)d, 64);
    a33r += __shfl_down(a33r, (unsigned)d, 64);
  }
  __shared__ float red[4][4];
  const int wv = threadIdx.x >> 6, ln = threadIdx.x & 63;
  if (ln == 0){ red[wv][0]=a9d; red[wv][1]=a9r; red[wv][2]=a33d; red[wv][3]=a33r; }
  __syncthreads();
  if (threadIdx.x < 4){
    double s = 0.0;
    #pragma unroll
    for (int w = 0; w < 4; ++w) s += (double)red[w][threadIdx.x];
    atomicAdd(&accum[(size_t)combo*6 + 2 + threadIdx.x], s);
  }
}

// ---------------- Final reduction -----------------
__global__ void fss_final(const double* __restrict__ accum, float* __restrict__ out)
{
  if (threadIdx.x == 0 && blockIdx.x == 0){
    const double HW = (double)HH*(double)WW;
    const double k4[3] = {1.0, 6561.0, 1185921.0};   // (k*k)^2
    double total = 0.0;
    for (int t = 0; t < NTH; ++t){
      for (int k = 0; k < 3; ++k){
        double s = 0.0;
        for (int img = 0; img < NB; ++img){
          const double* a = accum + (size_t)(img*NTH + t)*6 + (size_t)k*2;
          const double mse  = a[0] / (k4[k]*HW);
          const double mref = a[1] / (k4[k]*HW);
          s += 1.0 - mse/(mref + 1e-8);
        }
        total += s/(double)NB;
      }
    }
    out[0] = (float)(1.0 - total/9.0);
  }
}

extern "C" void kernel_launch(void* const* d_in, const int* in_sizes, int n_in,
                              void* d_out, int out_size, void* d_ws, size_t ws_size,
                              hipStream_t stream)
{
  const float* fcst = (const float*)d_in[0];
  const float* obs  = (const float*)d_in[1];
  float* out = (float*)d_out;
  double* accum = (double*)d_ws;
  QuadU* scr = (QuadU*)((char*)d_ws + ACC_BYTES);

  const size_t img_bytes = (size_t)NTH * WW * HH * sizeof(QuadU);   // 24 MB per image
  size_t avail = ws_size > (size_t)ACC_BYTES ? ws_size - ACC_BYTES : 0;
  int per = (int)(avail / img_bytes);
  if (per < 1) per = 1;
  if (per > NB) per = NB;

  hipMemsetAsync(d_ws, 0, ACC_BYTES, stream);
  for (int base = 0; base < NB; base += per){
    int n = NB - base; if (n > per) n = per;
    hipLaunchKernelGGL(fss_vert,  dim3(WW/256, HH/RBAND, n),     dim3(256), 0, stream,
                       fcst, obs, scr, accum, base);
    hipLaunchKernelGGL(fss_horiz, dim3(WW/XBAND, HH/256, NTH*n), dim3(256), 0, stream,
                       scr, accum, base);
  }
  hipLaunchKernelGGL(fss_final, dim3(1), dim3(64), 0, stream, accum, out);
}

// Round 3
// 416.494 us; speedup vs baseline: 2.9597x; 2.9597x over previous
//
#include <hip/hip_runtime.h>

#define HH 1024
#define WW 1024
#define NB 16
#define NTH 3
#define BAND 32
#define ACC_BYTES 4096

typedef unsigned int u32;
typedef _Float16 h2 __attribute__((ext_vector_type(2)));

__device__ __forceinline__ u32 pk2(float a, float b){
  h2 h; h[0] = (_Float16)a; h[1] = (_Float16)b;
  u32 r; __builtin_memcpy(&r, &h, 4); return r;
}

// sigmoid(10*(v-th)) for th = 0, 0.5, 1.0 sharing one exp:
// sig_t = 1 / (1 + e^{-10 v} * e^{10 th})
__device__ __forceinline__ void sig3(float v, float* sf){
  const float e = __expf(-10.0f * v);
  sf[0] = __fdividef(1.0f, 1.0f + e);
  sf[1] = __fdividef(1.0f, 1.0f + e*148.41315910257660f);
  sf[2] = __fdividef(1.0f, 1.0f + e*22026.465794806718f);
}
__device__ __forceinline__ void obs3(float v, float* so){
  so[0] = (v > 0.0f) ? 1.0f : 0.0f;
  so[1] = (v > 0.5f) ? 1.0f : 0.0f;
  so[2] = (v > 1.0f) ? 1.0f : 0.0f;
}

__global__ __launch_bounds__(1024, 4) void fss_fused(
    const float* __restrict__ fcst, const float* __restrict__ obs,
    double* __restrict__ accum)
{
  const int x   = threadIdx.x;            // column 0..1023
  const int y0  = blockIdx.x * BAND;      // band start row
  const int img = blockIdx.y;
  const int wv  = x >> 6, ln = x & 63;

  const float* F = fcst + (size_t)img*HH*WW;
  const float* O = obs  + (size_t)img*HH*WW;

  __shared__ u32   c9pk[2][NTH][WW];      // f16 pair (c9f, c9o), parity buffered
  __shared__ float L33f[2][NTH][WW];      // per-wave inclusive prefix of c33f
  __shared__ float L33o[2][NTH][WW];
  __shared__ float Tf[2][NTH][16];        // per-wave totals
  __shared__ float To[2][NTH][16];
  __shared__ float redu[16][18];

  float c9f[NTH]={0,0,0},  c9o[NTH]={0,0,0};
  float c33f[NTH]={0,0,0}, c33o[NTH]={0,0,0};
  float s1d[NTH]={0,0,0},  s1r[NTH]={0,0,0};
  float s9d[NTH]={0,0,0},  s9r[NTH]={0,0,0};
  float s33d[NTH]={0,0,0}, s33r[NTH]={0,0,0};

  // ---- warmup: rows [y0-16, y0+16] (uniform row guards; OOB rows contribute 0) ----
  #pragma unroll 1
  for (int r = y0-16; r <= y0+16; ++r){
    if ((unsigned)r >= HH) continue;
    const float fv = F[(size_t)r*WW + x];
    const float ov = O[(size_t)r*WW + x];
    float sf[NTH], so[NTH];
    sig3(fv, sf); obs3(ov, so);
    const bool in9  = (r >= y0-4) && (r <= y0+4);
    const bool ink1 = (r >= y0)   && (r <= y0+4);
    #pragma unroll
    for (int t = 0; t < NTH; ++t){
      c33f[t] += sf[t]; c33o[t] += so[t];
      if (in9){ c9f[t] += sf[t]; c9o[t] += so[t]; }
      if (ink1){ const float d = sf[t]-so[t];
                 s1d[t] += d*d; s1r[t] += sf[t]*sf[t] + so[t]*so[t]; }
    }
  }

  // ---- main loop: one barrier per row, parity-buffered LDS ----
  #pragma unroll 2
  for (int y = y0; y < y0 + BAND; ++y){
    const int p = y & 1;

    // phase 1: publish state centered at row y
    #pragma unroll
    for (int t = 0; t < NTH; ++t){
      c9pk[p][t][x] = pk2(c9f[t], c9o[t]);
      float lf = c33f[t], lo_ = c33o[t];
      #pragma unroll
      for (int d = 1; d < 64; d <<= 1){
        const float uf = __shfl_up(lf,  (unsigned)d, 64);
        const float uo = __shfl_up(lo_, (unsigned)d, 64);
        if (ln >= d){ lf += uf; lo_ += uo; }
      }
      L33f[p][t][x] = lf;
      L33o[p][t][x] = lo_;
      if (ln == 63){ Tf[p][t][wv] = lf; To[p][t][wv] = lo_; }
    }
    __syncthreads();

    // issue next-row loads early (uniform guards) so they overlap the LDS phase
    const int ri9 = y+5, ro9 = y-4, ri33 = y+17, ro33 = y-16;
    const bool bi9 = (ri9 < HH), bo9 = (ro9 >= 0), bi33 = (ri33 < HH), bo33 = (ro33 >= 0);
    float vi9f=0, vi9o=0, vo9f=0, vo9o=0, vi33f=0, vi33o=0, vo33f=0, vo33o=0;
    if (bi9 ){ vi9f  = F[(size_t)ri9 *WW + x]; vi9o  = O[(size_t)ri9 *WW + x]; }
    if (bo9 ){ vo9f  = F[(size_t)ro9 *WW + x]; vo9o  = O[(size_t)ro9 *WW + x]; }
    if (bi33){ vi33f = F[(size_t)ri33*WW + x]; vi33o = O[(size_t)ri33*WW + x]; }
    if (bo33){ vo33f = F[(size_t)ro33*WW + x]; vo33o = O[(size_t)ro33*WW + x]; }

    // phase 2: horizontal windows + stats for row y
    #pragma unroll
    for (int t = 0; t < NTH; ++t){
      h2 a = { (_Float16)0.0f, (_Float16)0.0f };
      #pragma unroll
      for (int j = -4; j <= 4; ++j){
        const int u = x + j;
        if ((unsigned)u < WW){
          const u32 w = c9pk[p][t][u];
          h2 hw; __builtin_memcpy(&hw, &w, 4);
          a += hw;                              // v_pk_add_f16
        }
      }
      const float h9f = (float)a[0], h9o = (float)a[1];

      const int hi = (x+16 < WW) ? x+16 : WW-1;
      const int lo = x - 17;
      float gf = L33f[p][t][hi], go = L33o[p][t][hi];
      if (lo >= 0){
        gf -= L33f[p][t][lo]; go -= L33o[p][t][lo];
        const int wlo = lo >> 6;
        if ((hi >> 6) != wlo){ gf += Tf[p][t][wlo]; go += To[p][t][wlo]; }
      }
      const float F9  = h9f*(1.0f/81.0f),   O9  = h9o*(1.0f/81.0f);
      const float d9  = F9 - O9;   s9d[t]  += d9*d9;   s9r[t]  += F9*F9 + O9*O9;
      const float F33 = gf*(1.0f/1089.0f),  O33 = go*(1.0f/1089.0f);
      const float d33 = F33 - O33; s33d[t] += d33*d33; s33r[t] += F33*F33 + O33*O33;
    }

    // phase 3: slide vertical windows to center y+1 (+ k=1 stats at entering row)
    if (bi9){
      float sf[NTH], so[NTH]; sig3(vi9f, sf); obs3(vi9o, so);
      const bool k1on = (ri9 < y0 + BAND);     // count each row exactly once per band
      #pragma unroll
      for (int t = 0; t < NTH; ++t){
        c9f[t] += sf[t]; c9o[t] += so[t];
        if (k1on){ const float d = sf[t]-so[t];
                   s1d[t] += d*d; s1r[t] += sf[t]*sf[t] + so[t]*so[t]; }
      }
    }
    if (bo9){
      float sf[NTH], so[NTH]; sig3(vo9f, sf); obs3(vo9o, so);
      #pragma unroll
      for (int t = 0; t < NTH; ++t){ c9f[t] -= sf[t]; c9o[t] -= so[t]; }
    }
    if (bi33){
      float sf[NTH], so[NTH]; sig3(vi33f, sf); obs3(vi33o, so);
      #pragma unroll
      for (int t = 0; t < NTH; ++t){ c33f[t] += sf[t]; c33o[t] += so[t]; }
    }
    if (bo33){
      float sf[NTH], so[NTH]; sig3(vo33f, sf); obs3(vo33o, so);
      #pragma unroll
      for (int t = 0; t < NTH; ++t){ c33f[t] -= sf[t]; c33o[t] -= so[t]; }
    }
    // no trailing barrier needed: next row writes the other parity buffer,
    // and the row-(y+1) barrier orders reads(p) before writes(p) of row y+2.
  }

  // ---- block reduction: 18 stats -> f64 atomics ----
  #define WRED(v) { _Pragma("unroll") \
    for (int d = 32; d; d >>= 1) v += __shfl_down(v, (unsigned)d, 64); }
  #pragma unroll
  for (int t = 0; t < NTH; ++t){
    WRED(s1d[t]);  WRED(s1r[t]);
    WRED(s9d[t]);  WRED(s9r[t]);
    WRED(s33d[t]); WRED(s33r[t]);
    if (ln == 0){
      redu[wv][t*6+0] = s1d[t];  redu[wv][t*6+1] = s1r[t];
      redu[wv][t*6+2] = s9d[t];  redu[wv][t*6+3] = s9r[t];
      redu[wv][t*6+4] = s33d[t]; redu[wv][t*6+5] = s33r[t];
    }
  }
  __syncthreads();
  if (x < 18){
    double s = 0.0;
    #pragma unroll
    for (int w = 0; w < 16; ++w) s += (double)redu[w][x];
    const int t = x / 6, j = x % 6;
    atomicAdd(&accum[(size_t)(img*NTH + t)*6 + j], s);
  }
}

__global__ void fss_final(const double* __restrict__ accum, float* __restrict__ out)
{
  if (threadIdx.x == 0 && blockIdx.x == 0){
    const double HW = (double)HH * (double)WW;
    double total = 0.0;
    for (int t = 0; t < NTH; ++t){
      for (int k = 0; k < 3; ++k){
        double s = 0.0;
        for (int img = 0; img < NB; ++img){
          const double* a = accum + (size_t)(img*NTH + t)*6 + (size_t)k*2;
          const double mse  = a[0] / HW;   // stats already in fraction units
          const double mref = a[1] / HW;
          s += 1.0 - mse / (mref + 1e-8);
        }
        total += s / (double)NB;
      }
    }
    out[0] = (float)(1.0 - total/9.0);
  }
}

extern "C" void kernel_launch(void* const* d_in, const int* in_sizes, int n_in,
                              void* d_out, int out_size, void* d_ws, size_t ws_size,
                              hipStream_t stream)
{
  const float* fcst = (const float*)d_in[0];
  const float* obs  = (const float*)d_in[1];
  float* out = (float*)d_out;
  double* accum = (double*)d_ws;

  hipMemsetAsync(d_ws, 0, ACC_BYTES, stream);
  hipLaunchKernelGGL(fss_fused, dim3(HH/BAND, NB), dim3(WW), 0, stream,
                     fcst, obs, accum);
  hipLaunchKernelGGL(fss_final, dim3(1), dim3(64), 0, stream, accum, out);
}